// Round 5
// baseline (284.988 us; speedup 1.0000x reference)
//
#include <hip/hip_runtime.h>

#define NN 50000
#define NE 800000
#define D 128
#define SEGBITS 12
#define SEGSZ 4096
#define NSEG 13          // ceil(50000/4096)
#define GRID_A 512
#define EPB ((NE + GRID_A - 1) / GRID_A)   // 1563

typedef __attribute__((ext_vector_type(8))) short short8;
typedef __attribute__((ext_vector_type(4))) float f32x4;

__device__ inline unsigned short f2bf(float f) {
    unsigned u = __builtin_bit_cast(unsigned, f);
    unsigned r = (u + 0x7fffu + ((u >> 16) & 1u)) >> 16;
    return (unsigned short)r;
}
__device__ inline float bflo(unsigned u) { return __builtin_bit_cast(float, u << 16); }
__device__ inline float bfhi(unsigned u) { return __builtin_bit_cast(float, u & 0xffff0000u); }

// ---------------- CSR build: atomic-free two-level counting sort ----------------

// A1: per-block coarse histogram (13 segments)
__global__ __launch_bounds__(256) void histA_kernel(const int* __restrict__ dst,
        int* __restrict__ bh) {
    __shared__ int h[NSEG];
    int t = threadIdx.x;
    if (t < NSEG) h[t] = 0;
    __syncthreads();
    int beg = blockIdx.x * EPB;
    int end = min(beg + EPB, NE);
    for (int e = beg + t; e < end; e += 256) atomicAdd(&h[dst[e] >> SEGBITS], 1);
    __syncthreads();
    if (t < NSEG) bh[t * GRID_A + blockIdx.x] = h[t];
}

// A2: scan per-segment over blocks; segment bases
__global__ __launch_bounds__(512) void scanA_kernel(const int* __restrict__ bh,
        int* __restrict__ bases, int* __restrict__ segBase) {
    __shared__ int s[512];
    __shared__ int carry;
    int t = threadIdx.x;
    if (t == 0) carry = 0;
    __syncthreads();
    for (int sg = 0; sg < NSEG; ++sg) {
        int v = bh[sg * GRID_A + t];
        s[t] = v;
        __syncthreads();
        #pragma unroll
        for (int off = 1; off < 512; off <<= 1) {
            int u = (t >= off) ? s[t - off] : 0;
            __syncthreads();
            s[t] += u;
            __syncthreads();
        }
        if (t == 0) segBase[sg] = carry;
        bases[sg * GRID_A + t] = carry + s[t] - v;
        __syncthreads();
        if (t == 511) carry += s[511];
        __syncthreads();
    }
    if (t == 0) segBase[NSEG] = carry;   // = NE
}

// A3: scatter edges into segment buckets, packed (dst_local<<16 | src)
__global__ __launch_bounds__(256) void scatA_kernel(const int* __restrict__ src,
        const int* __restrict__ dst, const int* __restrict__ bases,
        unsigned* __restrict__ bucket) {
    __shared__ int cur[NSEG];
    int t = threadIdx.x;
    if (t < NSEG) cur[t] = bases[t * GRID_A + blockIdx.x];
    __syncthreads();
    int beg = blockIdx.x * EPB;
    int end = min(beg + EPB, NE);
    for (int e = beg + t; e < end; e += 256) {
        int d = dst[e];
        int sg = d >> SEGBITS;
        int p = atomicAdd(&cur[sg], 1);          // LDS atomic
        bucket[p] = ((unsigned)(d & (SEGSZ - 1)) << 16) | (unsigned)src[e];
    }
}

// B: per-segment fine histogram + in-LDS scan -> rowptr slice + csr placement
__global__ __launch_bounds__(256) void buildB_kernel(const unsigned* __restrict__ bucket,
        const int* __restrict__ segBase, int* __restrict__ rowptr, int* __restrict__ csr) {
    __shared__ int h[SEGSZ];   // 16 KB
    __shared__ int s2[256];
    int sg = blockIdx.x;
    int t = threadIdx.x;
    int beg = segBase[sg], end = segBase[sg + 1];
    for (int i = t; i < SEGSZ; i += 256) h[i] = 0;
    __syncthreads();
    for (int i = beg + t; i < end; i += 256) atomicAdd(&h[bucket[i] >> 16], 1);  // LDS
    __syncthreads();
    // block-wide exclusive scan of h[0..4095]; thread t owns h[16t..16t+15]
    int base16 = t * 16;
    int sum = 0;
    #pragma unroll
    for (int j = 0; j < 16; ++j) sum += h[base16 + j];
    s2[t] = sum;
    __syncthreads();
    #pragma unroll
    for (int off = 1; off < 256; off <<= 1) {
        int u = (t >= off) ? s2[t - off] : 0;
        __syncthreads();
        s2[t] += u;
        __syncthreads();
    }
    int run = beg + s2[t] - sum;   // global csr offset for first node of this thread's strip
    int nbase = sg * SEGSZ;
    #pragma unroll
    for (int j = 0; j < 16; ++j) {
        int c = h[base16 + j];
        h[base16 + j] = run;                       // becomes placement cursor
        int n = nbase + base16 + j;
        if (n <= NN) rowptr[n] = run;              // covers rowptr[NN]=NE too
        run += c;
    }
    __syncthreads();
    for (int i = beg + t; i < end; i += 256) {
        unsigned v = bucket[i];
        int p = atomicAdd(&h[v >> 16], 1);         // LDS
        csr[p] = (int)(v & 0xFFFFu);
    }
}

// ---------------- pack weights into MFMA B-frag layout ----------------
// frag f = ct*4+kk, lane l: col = ct*16+(l&15), k = kk*32+(l>>4)*8+e
// flat short index (f*64+l)*8+e -> lane-linear 16B units, LDS conflict-free.

__global__ __launch_bounds__(256) void prep_w_kernel(const float* __restrict__ W0,
        const float* __restrict__ W1, const float* __restrict__ W2,
        const float* __restrict__ W3, unsigned short* __restrict__ O) {
    int t = blockIdx.x * 256 + threadIdx.x;   // 0..8191
    int w = t >> 11;
    int rem = t & 2047;
    int f = rem >> 6, l = rem & 63;
    int ct = f >> 2, kk = f & 3;
    int col = ct * 16 + (l & 15);
    int k0 = kk * 32 + (l >> 4) * 8;
    const float* W = (w == 0) ? W0 : (w == 1) ? W1 : (w == 2) ? W2 : W3;
    unsigned short* o = O + (size_t)w * 16384 + ((size_t)f * 64 + l) * 8;
    #pragma unroll
    for (int e = 0; e < 8; ++e) o[e] = f2bf(W[(k0 + e) * D + col]);
}

// ---------------- dual-output bf16 MFMA GEMM: Y = A@Wl, Z = A@Wr ----------------
// AFP32: A is fp32 row-major (converted to bf16 frags in-register)

template<int AFP32>
__global__ __launch_bounds__(256, 1) void gemm_kernel(const void* __restrict__ Av,
        const unsigned short* __restrict__ WfL, const unsigned short* __restrict__ WfR,
        unsigned short* __restrict__ Yb, unsigned short* __restrict__ Zb, int nrows) {
    __shared__ short8 sW[4096];   // Wl frags | Wr frags (64 KB)

    for (int i = threadIdx.x; i < 2048; i += 256) {
        sW[i]        = ((const short8*)WfL)[i];
        sW[i + 2048] = ((const short8*)WfR)[i];
    }
    __syncthreads();

    int wv = threadIdx.x >> 6, l = threadIdx.x & 63;
    int r15 = l & 15, kg = l >> 4;
    int row0 = blockIdx.x * 128 + wv * 32;

    short8 a[2][4];
    #pragma unroll
    for (int rt = 0; rt < 2; ++rt) {
        #pragma unroll
        for (int kk = 0; kk < 4; ++kk) {
            int row = row0 + rt * 16 + r15;
            row = min(row, nrows - 1);
            int off = kk * 32 + kg * 8;
            if (AFP32) {
                const float* A = (const float*)Av;
                float4 p = *(const float4*)(A + (size_t)row * D + off);
                float4 q = *(const float4*)(A + (size_t)row * D + off + 4);
                short8 v;
                v[0] = (short)f2bf(p.x); v[1] = (short)f2bf(p.y);
                v[2] = (short)f2bf(p.z); v[3] = (short)f2bf(p.w);
                v[4] = (short)f2bf(q.x); v[5] = (short)f2bf(q.y);
                v[6] = (short)f2bf(q.z); v[7] = (short)f2bf(q.w);
                a[rt][kk] = v;
            } else {
                const unsigned short* A = (const unsigned short*)Av;
                a[rt][kk] = *(const short8*)(A + (size_t)row * D + off);
            }
        }
    }

    f32x4 accY[2][8] = {};
    f32x4 accZ[2][8] = {};
    #pragma unroll
    for (int ct = 0; ct < 8; ++ct) {
        #pragma unroll
        for (int kk = 0; kk < 4; ++kk) {
            short8 bL = sW[(ct * 4 + kk) * 64 + l];
            short8 bR = sW[2048 + (ct * 4 + kk) * 64 + l];
            accY[0][ct] = __builtin_amdgcn_mfma_f32_16x16x32_bf16(a[0][kk], bL, accY[0][ct], 0, 0, 0);
            accY[1][ct] = __builtin_amdgcn_mfma_f32_16x16x32_bf16(a[1][kk], bL, accY[1][ct], 0, 0, 0);
            accZ[0][ct] = __builtin_amdgcn_mfma_f32_16x16x32_bf16(a[0][kk], bR, accZ[0][ct], 0, 0, 0);
            accZ[1][ct] = __builtin_amdgcn_mfma_f32_16x16x32_bf16(a[1][kk], bR, accZ[1][ct], 0, 0, 0);
        }
    }

    // C/D: col = ct*16+(lane&15), row = rt*16+(lane>>4)*4+i
    #pragma unroll
    for (int rt = 0; rt < 2; ++rt) {
        #pragma unroll
        for (int ct = 0; ct < 8; ++ct) {
            #pragma unroll
            for (int i = 0; i < 4; ++i) {
                int row = row0 + rt * 16 + kg * 4 + i;
                if (row < nrows) {
                    int col = ct * 16 + r15;
                    Yb[(size_t)row * D + col] = f2bf(accY[rt][ct][i]);
                    Zb[(size_t)row * D + col] = f2bf(accZ[rt][ct][i]);
                }
            }
        }
    }
}

// ---------------- mean-aggregate (bf16 gather) + epilogue ----------------

template<int RELU, int OUTBF16>
__global__ __launch_bounds__(256) void agg_ep_kernel(const unsigned short* __restrict__ Yb,
        const unsigned short* __restrict__ Zb, const float* __restrict__ bias,
        const int* __restrict__ rowptr, const int* __restrict__ csr,
        void* __restrict__ outp) {
    int lane = threadIdx.x & 63;
    int wv = (blockIdx.x << 2) + (threadIdx.x >> 6);
    int nw = gridDim.x << 2;
    float b0 = bias[lane * 2], b1 = bias[lane * 2 + 1];

    for (int node = wv; node < NN; node += nw) {
        int beg = rowptr[node], end = rowptr[node + 1];
        float a0 = 0.f, a1 = 0.f;
        int j = beg;
        for (; j + 3 < end; j += 4) {
            int s0 = csr[j], s1 = csr[j + 1], s2 = csr[j + 2], s3 = csr[j + 3];
            unsigned u0 = *(const unsigned*)(Yb + (size_t)s0 * D + lane * 2);
            unsigned u1 = *(const unsigned*)(Yb + (size_t)s1 * D + lane * 2);
            unsigned u2 = *(const unsigned*)(Yb + (size_t)s2 * D + lane * 2);
            unsigned u3 = *(const unsigned*)(Yb + (size_t)s3 * D + lane * 2);
            a0 += bflo(u0) + bflo(u1) + bflo(u2) + bflo(u3);
            a1 += bfhi(u0) + bfhi(u1) + bfhi(u2) + bfhi(u3);
        }
        for (; j < end; ++j) {
            unsigned u = *(const unsigned*)(Yb + (size_t)csr[j] * D + lane * 2);
            a0 += bflo(u);
            a1 += bfhi(u);
        }
        float inv = (end > beg) ? 1.f / (float)(end - beg) : 0.f;
        unsigned uz = *(const unsigned*)(Zb + (size_t)node * D + lane * 2);
        float v0 = a0 * inv + b0 + bflo(uz);
        float v1 = a1 * inv + b1 + bfhi(uz);
        if (RELU) { v0 = fmaxf(v0, 0.f); v1 = fmaxf(v1, 0.f); }
        if (OUTBF16) {
            unsigned o = (unsigned)f2bf(v0) | ((unsigned)f2bf(v1) << 16);
            *(unsigned*)((unsigned short*)outp + (size_t)node * D + lane * 2) = o;
        } else {
            float2 o; o.x = v0; o.y = v1;
            *(float2*)((float*)outp + (size_t)node * D + lane * 2) = o;
        }
    }
}

// ---------------- launch ----------------

extern "C" void kernel_launch(void* const* d_in, const int* in_sizes, int n_in,
                              void* d_out, int out_size, void* d_ws, size_t ws_size,
                              hipStream_t stream) {
    const float* x   = (const float*)d_in[0];
    const int*   ei  = (const int*)d_in[1];
    const float* W1l = (const float*)d_in[2];
    const float* b1  = (const float*)d_in[3];
    const float* W1r = (const float*)d_in[4];
    const float* W2l = (const float*)d_in[5];
    const float* b2  = (const float*)d_in[6];
    const float* W2r = (const float*)d_in[7];
    float* out = (float*)d_out;

    const int N = NN, E = NE;
    const int* src = ei;
    const int* dst = ei + E;

    char* ws = (char*)d_ws;
    size_t off = 0;
    auto alloc = [&](size_t bytes) -> void* {
        void* p = ws + off;
        off += (bytes + 255) & ~(size_t)255;
        return p;
    };
    int* rowptr  = (int*)alloc((size_t)(N + 1) * 4);
    int* csr     = (int*)alloc((size_t)E * 4);
    int* bh      = (int*)alloc((size_t)NSEG * GRID_A * 4);
    int* bases   = (int*)alloc((size_t)NSEG * GRID_A * 4);
    int* segBase = (int*)alloc((size_t)(NSEG + 1) * 4);
    unsigned* bucket = (unsigned*)alloc((size_t)E * 4);
    unsigned short* hb  = (unsigned short*)alloc((size_t)N * D * 2);
    unsigned short* Yb  = (unsigned short*)alloc((size_t)N * D * 2);
    unsigned short* Zb  = (unsigned short*)alloc((size_t)N * D * 2);
    unsigned short* wf  = (unsigned short*)alloc((size_t)4 * 16384 * 2);

    // CSR build (atomic-free counting sort)
    histA_kernel<<<GRID_A, 256, 0, stream>>>(dst, bh);
    scanA_kernel<<<1, 512, 0, stream>>>(bh, bases, segBase);
    scatA_kernel<<<GRID_A, 256, 0, stream>>>(src, dst, bases, bucket);
    buildB_kernel<<<NSEG, 256, 0, stream>>>(bucket, segBase, rowptr, csr);

    // weights -> frag layout
    prep_w_kernel<<<32, 256, 0, stream>>>(W1l, W1r, W2l, W2r, wf);

    unsigned short* wf1l = wf;
    unsigned short* wf1r = wf + 16384;
    unsigned short* wf2l = wf + 2 * 16384;
    unsigned short* wf2r = wf + 3 * 16384;

    int gblocks = (N + 127) / 128;

    // layer 1 (fp32 x consumed directly by gemm)
    gemm_kernel<1><<<gblocks, 256, 0, stream>>>(x, wf1l, wf1r, Yb, Zb, N);
    agg_ep_kernel<1, 1><<<2048, 256, 0, stream>>>(Yb, Zb, b1, rowptr, csr, hb);

    // layer 2
    gemm_kernel<0><<<gblocks, 256, 0, stream>>>(hb, wf2l, wf2r, Yb, Zb, N);
    agg_ep_kernel<0, 0><<<2048, 256, 0, stream>>>(Yb, Zb, b2, rowptr, csr, out);
}

// Round 6
// 144.656 us; speedup vs baseline: 1.9701x; 1.9701x over previous
//
#include <hip/hip_runtime.h>

#define NN 50000
#define NE 800000
#define D 128
#define SEGBITS 8
#define SEGSZ 256
#define NSEG 196         // ceil(50000/256)
#define GRID_A 512
#define EPB ((NE + GRID_A - 1) / GRID_A)   // 1563
#define FLAT (NSEG * GRID_A)               // 100352
#define SBLK ((FLAT + 255) / 256)          // 392

typedef __attribute__((ext_vector_type(8))) short short8;
typedef __attribute__((ext_vector_type(4))) float f32x4;

__device__ inline unsigned short f2bf(float f) {
    unsigned u = __builtin_bit_cast(unsigned, f);
    unsigned r = (u + 0x7fffu + ((u >> 16) & 1u)) >> 16;
    return (unsigned short)r;
}
__device__ inline float bflo(unsigned u) { return __builtin_bit_cast(float, u << 16); }
__device__ inline float bfhi(unsigned u) { return __builtin_bit_cast(float, u & 0xffff0000u); }

// ---------------- CSR build: atomic-free two-level counting sort ----------------
// bucket order = segment-major, then scatter-block-major: position of (sg, blk)
// chunk = exclusive-prefix over flattened bh[sg*GRID_A + blk].

// A1: per-block coarse histogram (196 segments)
__global__ __launch_bounds__(256) void histA_kernel(const int* __restrict__ dst,
        int* __restrict__ bh) {
    __shared__ int h[NSEG];
    int t = threadIdx.x;
    if (t < NSEG) h[t] = 0;
    __syncthreads();
    int beg = blockIdx.x * EPB;
    int end = min(beg + EPB, NE);
    for (int e = beg + t; e < end; e += 256) atomicAdd(&h[dst[e] >> SEGBITS], 1);
    __syncthreads();
    if (t < NSEG) bh[t * GRID_A + blockIdx.x] = h[t];
}

// A2: flat exclusive scan of bh[FLAT] -> bases; segment boundaries -> segBase
__global__ __launch_bounds__(256) void partialS_kernel(const int* __restrict__ bh,
        int* __restrict__ bsum) {
    __shared__ int s[256];
    int t = threadIdx.x;
    int i = blockIdx.x * 256 + t;
    s[t] = (i < FLAT) ? bh[i] : 0;
    __syncthreads();
    #pragma unroll
    for (int off = 128; off > 0; off >>= 1) {
        if (t < off) s[t] += s[t + off];
        __syncthreads();
    }
    if (t == 0) bsum[blockIdx.x] = s[0];
}

__global__ __launch_bounds__(512) void scanS_kernel(const int* __restrict__ bsum,
        int* __restrict__ boff) {
    __shared__ int s[512];
    int t = threadIdx.x;
    int v = (t < SBLK) ? bsum[t] : 0;
    s[t] = v;
    __syncthreads();
    #pragma unroll
    for (int off = 1; off < 512; off <<= 1) {
        int u = (t >= off) ? s[t - off] : 0;
        __syncthreads();
        s[t] += u;
        __syncthreads();
    }
    if (t < SBLK) boff[t] = s[t] - v;
}

__global__ __launch_bounds__(256) void scan2S_kernel(const int* __restrict__ bh,
        const int* __restrict__ boff, int* __restrict__ bases,
        int* __restrict__ segBase) {
    __shared__ int s[256];
    int t = threadIdx.x;
    int i = blockIdx.x * 256 + t;
    int v = (i < FLAT) ? bh[i] : 0;
    s[t] = v;
    __syncthreads();
    #pragma unroll
    for (int off = 1; off < 256; off <<= 1) {
        int u = (t >= off) ? s[t - off] : 0;
        __syncthreads();
        s[t] += u;
        __syncthreads();
    }
    if (i < FLAT) {
        int excl = s[t] - v + boff[blockIdx.x];
        bases[i] = excl;
        if ((i & (GRID_A - 1)) == 0) segBase[i >> 9] = excl;   // GRID_A = 512
    }
    if (i == 0) segBase[NSEG] = NE;
}

// A3: scatter edges into segment buckets, packed (dst_local<<24 | src)
__global__ __launch_bounds__(256) void scatA_kernel(const int* __restrict__ src,
        const int* __restrict__ dst, const int* __restrict__ bases,
        unsigned* __restrict__ bucket) {
    __shared__ int cur[NSEG];
    int t = threadIdx.x;
    if (t < NSEG) cur[t] = bases[t * GRID_A + blockIdx.x];
    __syncthreads();
    int beg = blockIdx.x * EPB;
    int end = min(beg + EPB, NE);
    for (int e = beg + t; e < end; e += 256) {
        int d = dst[e];
        int sg = d >> SEGBITS;
        int p = atomicAdd(&cur[sg], 1);          // LDS atomic
        bucket[p] = ((unsigned)(d & (SEGSZ - 1)) << 24) | (unsigned)src[e];
    }
}

// B: per-segment fine histogram (1 bin/thread) + in-LDS scan -> rowptr + csr
__global__ __launch_bounds__(256) void buildB_kernel(const unsigned* __restrict__ bucket,
        const int* __restrict__ segBase, int* __restrict__ rowptr, int* __restrict__ csr) {
    __shared__ int h[SEGSZ];    // 1 KB, bin t owned by thread t
    __shared__ int s[SEGSZ];
    int sg = blockIdx.x;
    int t = threadIdx.x;
    int beg = segBase[sg], end = segBase[sg + 1];
    h[t] = 0;
    __syncthreads();
    for (int i = beg + t; i < end; i += 256) atomicAdd(&h[bucket[i] >> 24], 1);  // LDS
    __syncthreads();
    int v = h[t];
    s[t] = v;
    __syncthreads();
    #pragma unroll
    for (int off = 1; off < 256; off <<= 1) {
        int u = (t >= off) ? s[t - off] : 0;
        __syncthreads();
        s[t] += u;
        __syncthreads();
    }
    int excl = beg + s[t] - v;
    int n = sg * SEGSZ + t;
    if (n <= NN) rowptr[n] = excl;      // covers rowptr[NN] = NE (node 50000 -> sg 195, t 80)
    h[t] = excl;                        // becomes placement cursor
    __syncthreads();
    for (int i = beg + t; i < end; i += 256) {
        unsigned u = bucket[i];
        int p = atomicAdd(&h[u >> 24], 1);       // LDS
        csr[p] = (int)(u & 0xFFFFFFu);
    }
}

// ---------------- pack weights into MFMA B-frag layout ----------------
// frag f = ct*4+kk, lane l: col = ct*16+(l&15), k = kk*32+(l>>4)*8+e
// flat short index (f*64+l)*8+e -> lane-linear 16B units, LDS conflict-free.

__global__ __launch_bounds__(256) void prep_w_kernel(const float* __restrict__ W0,
        const float* __restrict__ W1, const float* __restrict__ W2,
        const float* __restrict__ W3, unsigned short* __restrict__ O) {
    int t = blockIdx.x * 256 + threadIdx.x;   // 0..8191
    int w = t >> 11;
    int rem = t & 2047;
    int f = rem >> 6, l = rem & 63;
    int ct = f >> 2, kk = f & 3;
    int col = ct * 16 + (l & 15);
    int k0 = kk * 32 + (l >> 4) * 8;
    const float* W = (w == 0) ? W0 : (w == 1) ? W1 : (w == 2) ? W2 : W3;
    unsigned short* o = O + (size_t)w * 16384 + ((size_t)f * 64 + l) * 8;
    #pragma unroll
    for (int e = 0; e < 8; ++e) o[e] = f2bf(W[(k0 + e) * D + col]);
}

// ---------------- dual-output bf16 MFMA GEMM: Y = A@Wl, Z = A@Wr ----------------
// AFP32: A is fp32 row-major (converted to bf16 frags in-register)

template<int AFP32>
__global__ __launch_bounds__(256, 1) void gemm_kernel(const void* __restrict__ Av,
        const unsigned short* __restrict__ WfL, const unsigned short* __restrict__ WfR,
        unsigned short* __restrict__ Yb, unsigned short* __restrict__ Zb, int nrows) {
    __shared__ short8 sW[4096];   // Wl frags | Wr frags (64 KB)

    for (int i = threadIdx.x; i < 2048; i += 256) {
        sW[i]        = ((const short8*)WfL)[i];
        sW[i + 2048] = ((const short8*)WfR)[i];
    }
    __syncthreads();

    int wv = threadIdx.x >> 6, l = threadIdx.x & 63;
    int r15 = l & 15, kg = l >> 4;
    int row0 = blockIdx.x * 128 + wv * 32;

    short8 a[2][4];
    #pragma unroll
    for (int rt = 0; rt < 2; ++rt) {
        #pragma unroll
        for (int kk = 0; kk < 4; ++kk) {
            int row = row0 + rt * 16 + r15;
            row = min(row, nrows - 1);
            int off = kk * 32 + kg * 8;
            if (AFP32) {
                const float* A = (const float*)Av;
                float4 p = *(const float4*)(A + (size_t)row * D + off);
                float4 q = *(const float4*)(A + (size_t)row * D + off + 4);
                short8 v;
                v[0] = (short)f2bf(p.x); v[1] = (short)f2bf(p.y);
                v[2] = (short)f2bf(p.z); v[3] = (short)f2bf(p.w);
                v[4] = (short)f2bf(q.x); v[5] = (short)f2bf(q.y);
                v[6] = (short)f2bf(q.z); v[7] = (short)f2bf(q.w);
                a[rt][kk] = v;
            } else {
                const unsigned short* A = (const unsigned short*)Av;
                a[rt][kk] = *(const short8*)(A + (size_t)row * D + off);
            }
        }
    }

    f32x4 accY[2][8] = {};
    f32x4 accZ[2][8] = {};
    #pragma unroll
    for (int ct = 0; ct < 8; ++ct) {
        #pragma unroll
        for (int kk = 0; kk < 4; ++kk) {
            short8 bL = sW[(ct * 4 + kk) * 64 + l];
            short8 bR = sW[2048 + (ct * 4 + kk) * 64 + l];
            accY[0][ct] = __builtin_amdgcn_mfma_f32_16x16x32_bf16(a[0][kk], bL, accY[0][ct], 0, 0, 0);
            accY[1][ct] = __builtin_amdgcn_mfma_f32_16x16x32_bf16(a[1][kk], bL, accY[1][ct], 0, 0, 0);
            accZ[0][ct] = __builtin_amdgcn_mfma_f32_16x16x32_bf16(a[0][kk], bR, accZ[0][ct], 0, 0, 0);
            accZ[1][ct] = __builtin_amdgcn_mfma_f32_16x16x32_bf16(a[1][kk], bR, accZ[1][ct], 0, 0, 0);
        }
    }

    // C/D: col = ct*16+(lane&15), row = rt*16+(lane>>4)*4+i
    #pragma unroll
    for (int rt = 0; rt < 2; ++rt) {
        #pragma unroll
        for (int ct = 0; ct < 8; ++ct) {
            #pragma unroll
            for (int i = 0; i < 4; ++i) {
                int row = row0 + rt * 16 + kg * 4 + i;
                if (row < nrows) {
                    int col = ct * 16 + r15;
                    Yb[(size_t)row * D + col] = f2bf(accY[rt][ct][i]);
                    Zb[(size_t)row * D + col] = f2bf(accZ[rt][ct][i]);
                }
            }
        }
    }
}

// ---------------- mean-aggregate (bf16 gather) + epilogue ----------------

template<int RELU, int OUTBF16>
__global__ __launch_bounds__(256) void agg_ep_kernel(const unsigned short* __restrict__ Yb,
        const unsigned short* __restrict__ Zb, const float* __restrict__ bias,
        const int* __restrict__ rowptr, const int* __restrict__ csr,
        void* __restrict__ outp) {
    int lane = threadIdx.x & 63;
    int wv = (blockIdx.x << 2) + (threadIdx.x >> 6);
    int nw = gridDim.x << 2;
    float b0 = bias[lane * 2], b1 = bias[lane * 2 + 1];

    for (int node = wv; node < NN; node += nw) {
        int beg = rowptr[node], end = rowptr[node + 1];
        float a0 = 0.f, a1 = 0.f;
        int j = beg;
        for (; j + 3 < end; j += 4) {
            int s0 = csr[j], s1 = csr[j + 1], s2 = csr[j + 2], s3 = csr[j + 3];
            unsigned u0 = *(const unsigned*)(Yb + (size_t)s0 * D + lane * 2);
            unsigned u1 = *(const unsigned*)(Yb + (size_t)s1 * D + lane * 2);
            unsigned u2 = *(const unsigned*)(Yb + (size_t)s2 * D + lane * 2);
            unsigned u3 = *(const unsigned*)(Yb + (size_t)s3 * D + lane * 2);
            a0 += bflo(u0) + bflo(u1) + bflo(u2) + bflo(u3);
            a1 += bfhi(u0) + bfhi(u1) + bfhi(u2) + bfhi(u3);
        }
        for (; j < end; ++j) {
            unsigned u = *(const unsigned*)(Yb + (size_t)csr[j] * D + lane * 2);
            a0 += bflo(u);
            a1 += bfhi(u);
        }
        float inv = (end > beg) ? 1.f / (float)(end - beg) : 0.f;
        unsigned uz = *(const unsigned*)(Zb + (size_t)node * D + lane * 2);
        float v0 = a0 * inv + b0 + bflo(uz);
        float v1 = a1 * inv + b1 + bfhi(uz);
        if (RELU) { v0 = fmaxf(v0, 0.f); v1 = fmaxf(v1, 0.f); }
        if (OUTBF16) {
            unsigned o = (unsigned)f2bf(v0) | ((unsigned)f2bf(v1) << 16);
            *(unsigned*)((unsigned short*)outp + (size_t)node * D + lane * 2) = o;
        } else {
            float2 o; o.x = v0; o.y = v1;
            *(float2*)((float*)outp + (size_t)node * D + lane * 2) = o;
        }
    }
}

// ---------------- launch ----------------

extern "C" void kernel_launch(void* const* d_in, const int* in_sizes, int n_in,
                              void* d_out, int out_size, void* d_ws, size_t ws_size,
                              hipStream_t stream) {
    const float* x   = (const float*)d_in[0];
    const int*   ei  = (const int*)d_in[1];
    const float* W1l = (const float*)d_in[2];
    const float* b1  = (const float*)d_in[3];
    const float* W1r = (const float*)d_in[4];
    const float* W2l = (const float*)d_in[5];
    const float* b2  = (const float*)d_in[6];
    const float* W2r = (const float*)d_in[7];
    float* out = (float*)d_out;

    const int N = NN, E = NE;
    const int* src = ei;
    const int* dst = ei + E;

    char* ws = (char*)d_ws;
    size_t off = 0;
    auto alloc = [&](size_t bytes) -> void* {
        void* p = ws + off;
        off += (bytes + 255) & ~(size_t)255;
        return p;
    };
    int* rowptr  = (int*)alloc((size_t)(N + 1) * 4);
    int* csr     = (int*)alloc((size_t)E * 4);
    int* bh      = (int*)alloc((size_t)FLAT * 4);
    int* bases   = (int*)alloc((size_t)FLAT * 4);
    int* bsumS   = (int*)alloc((size_t)SBLK * 4);
    int* boffS   = (int*)alloc((size_t)SBLK * 4);
    int* segBase = (int*)alloc((size_t)(NSEG + 1) * 4);
    unsigned* bucket = (unsigned*)alloc((size_t)E * 4);
    unsigned short* hb  = (unsigned short*)alloc((size_t)N * D * 2);
    unsigned short* Yb  = (unsigned short*)alloc((size_t)N * D * 2);
    unsigned short* Zb  = (unsigned short*)alloc((size_t)N * D * 2);
    unsigned short* wf  = (unsigned short*)alloc((size_t)4 * 16384 * 2);

    // CSR build (atomic-free counting sort, two-level)
    histA_kernel<<<GRID_A, 256, 0, stream>>>(dst, bh);
    partialS_kernel<<<SBLK, 256, 0, stream>>>(bh, bsumS);
    scanS_kernel<<<1, 512, 0, stream>>>(bsumS, boffS);
    scan2S_kernel<<<SBLK, 256, 0, stream>>>(bh, boffS, bases, segBase);
    scatA_kernel<<<GRID_A, 256, 0, stream>>>(src, dst, bases, bucket);
    buildB_kernel<<<NSEG, 256, 0, stream>>>(bucket, segBase, rowptr, csr);

    // weights -> frag layout
    prep_w_kernel<<<32, 256, 0, stream>>>(W1l, W1r, W2l, W2r, wf);

    unsigned short* wf1l = wf;
    unsigned short* wf1r = wf + 16384;
    unsigned short* wf2l = wf + 2 * 16384;
    unsigned short* wf2r = wf + 3 * 16384;

    int gblocks = (N + 127) / 128;

    // layer 1 (fp32 x consumed directly by gemm)
    gemm_kernel<1><<<gblocks, 256, 0, stream>>>(x, wf1l, wf1r, Yb, Zb, N);
    agg_ep_kernel<1, 1><<<2048, 256, 0, stream>>>(Yb, Zb, b1, rowptr, csr, hb);

    // layer 2
    gemm_kernel<0><<<gblocks, 256, 0, stream>>>(hb, wf2l, wf2r, Yb, Zb, N);
    agg_ep_kernel<0, 0><<<2048, 256, 0, stream>>>(Yb, Zb, b2, rowptr, csr, out);
}